// Round 1
// 610.410 us; speedup vs baseline: 1.0101x; 1.0101x over previous
//
#include <hip/hip_runtime.h>
#include <hip/hip_bf16.h>

// Fused Comm_OUT pipeline, batch-row-parallel (GRU recurrence is per-row).
// Round-8: latency-attack. Counters showed MfmaUtil 7%, VALU 16%, HBM 14%,
// Occ 23% -> latency-bound (~126 cy per weight-load tx, loads serialized).
// Change: 16 waves/block (1024 thr), each wave owns 16 cols (old (cg,j)
// pair -> wave). Same device-wide weight-tx count, 2x resident waves ->
// 2x in-flight loads. Halved accumulator state funds register-resident
// Wc fragments (loop Wc stream deleted, -24% loop tx).
// 256 blocks x 1024 threads (16 waves), BM=32, 1 block/CU, VGPR cap 128.
// Runtime dtype detection (inputs fp32 or bf16) via g_flag.

typedef __attribute__((ext_vector_type(8))) short bf16x8;   // 8 x bf16 (4 VGPRs)
typedef __attribute__((ext_vector_type(4))) float f32x4;    // MFMA accumulator

#define MFMA16(a, b, c) __builtin_amdgcn_mfma_f32_16x16x32_bf16((a), (b), (c), 0, 0, 0)

constexpr int F   = 640;
constexpr int H   = 256;
constexpr int LSTEPS = 20;
constexpr int CO  = 32;
constexpr int LDP = 264;   // padded bf16 row stride (16B-aligned rows)

// packed-weight element offsets inside g_wpk
constexpr size_t WHH_E  = 0;                    // 8cg*3g*8kk*2j*64lane*8 = 196608
constexpr size_t WIH_E  = 196608;               // 196608
constexpr size_t WC_E   = 393216;               // 8cg*8kk*2j*64*8       = 65536
constexpr size_t WMU_E  = 458752;               // 2w*8kk*64*8           = 8192
constexpr size_t WLIN_E = 466944;               // 8cg*20kk*2j*64*8      = 163840
constexpr size_t PK_ELEMS = 630784;

__device__ __align__(16) unsigned short g_wpk[PK_ELEMS];
__device__ int g_flag;     // 1 = inputs are fp32

__device__ __forceinline__ float bf2f(__hip_bfloat16 x) { return __bfloat162float(x); }
__device__ __forceinline__ unsigned short f2bs(float f) {
    __hip_bfloat16 h = __float2bfloat16(f);
    return *reinterpret_cast<unsigned short*>(&h);
}
__device__ __forceinline__ bf16x8 lds8(const unsigned short* p) {
    return *reinterpret_cast<const bf16x8*>(p);
}
__device__ __forceinline__ bf16x8 pk8(size_t eoff) {
    return *reinterpret_cast<const bf16x8*>(g_wpk + eoff);
}
__device__ __forceinline__ float sigm(float x) {
    return 1.0f / (1.0f + __expf(-x));
}

template<bool F32>
__device__ __forceinline__ bf16x8 g8(const void* base, size_t off) {
    if constexpr (!F32) {
        return *reinterpret_cast<const bf16x8*>((const __hip_bfloat16*)base + off);
    } else {
        const float* f = (const float*)base + off;
        float4 lo = *reinterpret_cast<const float4*>(f);
        float4 hi = *reinterpret_cast<const float4*>(f + 4);
        bf16x8 r;
        r[0] = (short)f2bs(lo.x); r[1] = (short)f2bs(lo.y);
        r[2] = (short)f2bs(lo.z); r[3] = (short)f2bs(lo.w);
        r[4] = (short)f2bs(hi.x); r[5] = (short)f2bs(hi.y);
        r[6] = (short)f2bs(hi.z); r[7] = (short)f2bs(hi.w);
        return r;
    }
}

template<bool F32>
__device__ __forceinline__ float ld1(const void* base, int i) {
    if constexpr (!F32) return bf2f(((const __hip_bfloat16*)base)[i]);
    else                return ((const float*)base)[i];
}

// ---------------- dtype detect: v1 (uniform[0.5,1.5]) ----------------
__global__ void detect_dtype(const void* v1) {
    const unsigned short* u = (const unsigned short*)v1;
    int f32 = 0;
    for (int i = 0; i < 8; ++i) {
        unsigned short s = u[i];
        __hip_bfloat16 h = *reinterpret_cast<__hip_bfloat16*>(&s);
        float v = __bfloat162float(h);
        if (!(v >= 0.25f && v <= 2.0f)) f32 = 1;
    }
    g_flag = f32;
}

// ---------------- weight pre-pack (fp32|bf16 -> bf16 fragment streams) ----------------
__device__ __forceinline__ unsigned short cvt1(const void* p, size_t i, bool f32) {
    if (f32) return f2bs(((const float*)p)[i]);
    return ((const unsigned short*)p)[i];
}

__global__ void prepack(const void* Wlin, const void* Wih, const void* Whh,
                        const void* Wc, const void* Wmu) {
    const bool f32 = (g_flag != 0);
    const int gid = blockIdx.x * 256 + threadIdx.x;
    const void* src;
    size_t dbase;
    int row, col0, ncols;
    if (gid < 24576) {                       // Whh [768,256]
        int idx = gid;
        int lane = idx & 63, j = (idx >> 6) & 1, kk = (idx >> 7) & 7;
        int t2 = idx >> 10, g = t2 % 3, w = t2 / 3;
        row = g * 256 + w * 32 + j * 16 + (lane & 15);
        col0 = kk * 32 + (lane >> 4) * 8;
        ncols = 256; src = Whh; dbase = WHH_E + (size_t)idx * 8;
    } else if (gid < 49152) {                // Wih [768,256]
        int idx = gid - 24576;
        int lane = idx & 63, j = (idx >> 6) & 1, kk = (idx >> 7) & 7;
        int t2 = idx >> 10, g = t2 % 3, w = t2 / 3;
        row = g * 256 + w * 32 + j * 16 + (lane & 15);
        col0 = kk * 32 + (lane >> 4) * 8;
        ncols = 256; src = Wih; dbase = WIH_E + (size_t)idx * 8;
    } else if (gid < 57344) {                // Wc [256,256]
        int idx = gid - 49152;
        int lane = idx & 63, j = (idx >> 6) & 1, kk = (idx >> 7) & 7, w = idx >> 10;
        row = w * 32 + j * 16 + (lane & 15);
        col0 = kk * 32 + (lane >> 4) * 8;
        ncols = 256; src = Wc; dbase = WC_E + (size_t)idx * 8;
    } else if (gid < 58368) {                // Wmu [32,256]
        int idx = gid - 57344;
        int lane = idx & 63, kk = (idx >> 6) & 7, w = idx >> 9;
        row = w * 16 + (lane & 15);
        col0 = kk * 32 + (lane >> 4) * 8;
        ncols = 256; src = Wmu; dbase = WMU_E + (size_t)idx * 8;
    } else if (gid < 78848) {                // Wlin [256,640]
        int idx = gid - 58368;
        int lane = idx & 63, j = (idx >> 6) & 1;
        int t1 = idx >> 7, kk = t1 % 20, w = t1 / 20;
        row = w * 32 + j * 16 + (lane & 15);
        col0 = kk * 32 + (lane >> 4) * 8;
        ncols = 640; src = Wlin; dbase = WLIN_E + (size_t)idx * 8;
    } else {
        return;
    }
    const size_t s0 = (size_t)row * ncols + col0;
    #pragma unroll
    for (int i = 0; i < 8; ++i) g_wpk[dbase + i] = cvt1(src, s0 + i, f32);
}

// ---------------- FAST PATH: BM=32, 1024 threads, 16 waves, 16 cols/wave ----------------
template<bool F32>
__device__ __forceinline__ void fast_pipe(
    const void* hw, const void* blin,
    const void* g1, const void* be1, const void* m1, const void* v1, const void* a1,
    const void* bih, const void* bhh,
    const void* g2, const void* be2, const void* m2, const void* v2, const void* a2,
    const void* bc,
    const void* g3, const void* be3, const void* m3, const void* v3, const void* a3,
    const void* bmu,
    void* out,
    unsigned short* hb, unsigned short* yb, unsigned short* zb)
{
    const int tid  = threadIdx.x;
    const int cg   = tid >> 6;        // wave = 16-col group, 0..15
    const int cgo  = cg >> 1;         // packed-layout 32-col group
    const int jj   = cg & 1;          // 16-col half inside cgo
    const int lane = tid & 63;
    const int m16  = lane & 15;
    const int q    = lane >> 4;
    const int row0 = blockIdx.x * 32;
    const int c0   = cg * 16 + m16;   // this lane's output column
    const size_t lane8 = (size_t)lane * 8;

    // persistent per-step params (folded), scalar per lane now
    float s2v, t2v, s3v, t3f, bhhn;
    {
        float s;
        s = ld1<F32>(g2, c0) * rsqrtf(ld1<F32>(v2, c0) + 1e-5f);
        s2v = s; t2v = ld1<F32>(be2, c0) - ld1<F32>(m2, c0) * s;
        s = ld1<F32>(g3, c0) * rsqrtf(ld1<F32>(v3, c0) + 1e-5f);
        s3v = s;
        t3f = (ld1<F32>(bc, c0) - ld1<F32>(m3, c0)) * s + ld1<F32>(be3, c0);
        bhhn = ld1<F32>(bhh, 2 * H + c0);
    }
    const float a2v = ld1<F32>(a2, 0), a3v = ld1<F32>(a3, 0);

    // ---- Phase 1: x = prelu(bn1(rows @ Wlin^T + blin)) -> yb ----
    {
        f32x4 xacc[2] = {};   // [mt]
        #pragma unroll 5
        for (int kk = 0; kk < F / 32; ++kk) {
            bf16x8 fa0 = g8<F32>(hw, (size_t)(row0 + m16) * F + kk * 32 + q * 8);
            bf16x8 fa1 = g8<F32>(hw, (size_t)(row0 + 16 + m16) * F + kk * 32 + q * 8);
            bf16x8 b0 = pk8(WLIN_E + (size_t)((cgo * 20 + kk) * 2 + jj) * 512 + lane8);
            xacc[0] = MFMA16(fa0, b0, xacc[0]);
            xacc[1] = MFMA16(fa1, b0, xacc[1]);
        }
        float s = ld1<F32>(g1, c0) * rsqrtf(ld1<F32>(v1, c0) + 1e-5f);
        float t = ld1<F32>(be1, c0) - ld1<F32>(m1, c0) * s;
        float bl = ld1<F32>(blin, c0);
        float av = ld1<F32>(a1, 0);
        #pragma unroll
        for (int mt = 0; mt < 2; ++mt)
            #pragma unroll
            for (int r = 0; r < 4; ++r) {
                float vv = (xacc[mt][r] + bl) * s + t;
                vv = (vv >= 0.0f) ? vv : av * vv;
                yb[(mt * 16 + q * 4 + r) * LDP + c0] = f2bs(vv);
            }
    }
    __syncthreads();   // x visible in yb

    // ---- Phase 2: gi = x @ Wih^T + (bih + bhh[r,z])  (registers) ----
    f32x4 gi[2][3] = {};   // [mt][g]
    {
        const unsigned short* xa0 = yb + m16 * LDP + q * 8;
        const unsigned short* xa1 = xa0 + 16 * LDP;
        #pragma unroll
        for (int g = 0; g < 3; ++g)
            #pragma unroll
            for (int kk = 0; kk < 8; ++kk) {
                bf16x8 fa0 = lds8(xa0 + kk * 32);
                bf16x8 fa1 = lds8(xa1 + kk * 32);
                bf16x8 b0 = pk8(WIH_E + (size_t)(((cgo * 3 + g) * 8 + kk) * 2 + jj) * 512 + lane8);
                gi[0][g] = MFMA16(fa0, b0, gi[0][g]);
                gi[1][g] = MFMA16(fa1, b0, gi[1][g]);
            }
        #pragma unroll
        for (int g = 0; g < 3; ++g) {
            float bias = ld1<F32>(bih, g * H + c0);
            if (g < 2) bias += ld1<F32>(bhh, g * H + c0);
            #pragma unroll
            for (int mt = 0; mt < 2; ++mt)
                #pragma unroll
                for (int r = 0; r < 4; ++r) gi[mt][g][r] += bias;
        }
    }

    // ---- register-resident Wc fragments (invariant across all 20 steps) ----
    bf16x8 wcf[8];
    #pragma unroll
    for (int kk = 0; kk < 8; ++kk)
        wcf[kk] = pk8(WC_E + (size_t)((cgo * 8 + kk) * 2 + jj) * 512 + lane8);

    // ---- GRU loop + fused downstream ----
    // Per step t: [gh reads hb(t-1)] [gates] A [write hb,yb] B1
    //             [Wc reads yb -> zb] B2 [Wmu reads zb -> out]
    float hreg[2][4] = {};
    const unsigned short* ha0 = hb + m16 * LDP + q * 8;
    const unsigned short* ha1 = ha0 + 16 * LDP;
    const unsigned short* ya0 = yb + m16 * LDP + q * 8;
    const unsigned short* ya1 = ya0 + 16 * LDP;
    const int mto = (cg >> 1) & 1;
    const int nto = cg & 1;
    const unsigned short* zaP = zb + (mto * 16 + m16) * LDP + q * 8;
    const float bmuv = (cg < 4) ? ld1<F32>(bmu, nto * 16 + m16) : 0.0f;

    #pragma unroll 1
    for (int t = 0; t < LSTEPS; ++t) {
        f32x4 gh[2][3] = {};
        if (t > 0) {
            #pragma unroll
            for (int g = 0; g < 3; ++g)
                #pragma unroll
                for (int kk = 0; kk < 8; ++kk) {
                    bf16x8 fa0 = lds8(ha0 + kk * 32);
                    bf16x8 fa1 = lds8(ha1 + kk * 32);
                    bf16x8 b0 = pk8(WHH_E + (size_t)(((cgo * 3 + g) * 8 + kk) * 2 + jj) * 512 + lane8);
                    gh[0][g] = MFMA16(fa0, b0, gh[0][g]);
                    gh[1][g] = MFMA16(fa1, b0, gh[1][g]);
                }
        }
        // gates + h update + y = prelu(bn2(h))
        float yv[2][4];
        #pragma unroll
        for (int mt = 0; mt < 2; ++mt)
            #pragma unroll
            for (int r = 0; r < 4; ++r) {
                float rr = sigm(gi[mt][0][r] + gh[mt][0][r]);
                float zz = sigm(gi[mt][1][r] + gh[mt][1][r]);
                float nin = gi[mt][2][r] + rr * (gh[mt][2][r] + bhhn);
                float nn = 2.0f * sigm(2.0f * nin) - 1.0f;   // tanh
                float hh = (1.0f - zz) * nn + zz * hreg[mt][r];
                hreg[mt][r] = hh;
                float y = hh * s2v + t2v;
                yv[mt][r] = (y >= 0.0f) ? y : a2v * y;
            }
        __syncthreads();   // A: all reads of hb/yb/zb from prior phases done
        #pragma unroll
        for (int mt = 0; mt < 2; ++mt)
            #pragma unroll
            for (int r = 0; r < 4; ++r) {
                const int idx = (mt * 16 + q * 4 + r) * LDP + c0;
                hb[idx] = f2bs(hreg[mt][r]);
                yb[idx] = f2bs(yv[mt][r]);
            }
        __syncthreads();   // B1: h/y visible

        // w2 = y @ Wc^T -> z -> zb  (Wc fragments register-resident)
        f32x4 w2[2] = {};
        #pragma unroll
        for (int kk = 0; kk < 8; ++kk) {
            bf16x8 fa0 = lds8(ya0 + kk * 32);
            bf16x8 fa1 = lds8(ya1 + kk * 32);
            w2[0] = MFMA16(fa0, wcf[kk], w2[0]);
            w2[1] = MFMA16(fa1, wcf[kk], w2[1]);
        }
        #pragma unroll
        for (int mt = 0; mt < 2; ++mt)
            #pragma unroll
            for (int r = 0; r < 4; ++r) {
                float z0 = w2[mt][r] * s3v + t3f;
                z0 = (z0 >= 0.0f) ? z0 : a3v * z0;
                zb[(mt * 16 + q * 4 + r) * LDP + c0] = f2bs(z0);
            }
        __syncthreads();   // B2: z visible

        // out_t = z @ Wmu^T + bmu   (waves 0..3 own the four 16x16 tiles)
        if (cg < 4) {
            f32x4 o = {};
            #pragma unroll
            for (int kk = 0; kk < 8; ++kk) {
                bf16x8 a = lds8(zaP + kk * 32);
                bf16x8 b = pk8(WMU_E + (size_t)(nto * 8 + kk) * 512 + lane8);
                o = MFMA16(a, b, o);
            }
            #pragma unroll
            for (int r = 0; r < 4; ++r) {
                float vv = o[r] + bmuv;
                const size_t oi = (size_t)(row0 + mto * 16 + q * 4 + r) * (LSTEPS * CO)
                                + t * CO + nto * 16 + m16;
                if constexpr (F32) ((float*)out)[oi] = vv;
                else               ((__hip_bfloat16*)out)[oi] = __float2bfloat16(vv);
            }
        }
        // safe: zb rewritten only after B2(t+1); hb/yb rewritten only after A(t+1)
    }
}

__global__ __launch_bounds__(1024, 4) void comm_fast(
    const void* hw, const void* blin,
    const void* g1, const void* be1, const void* m1, const void* v1, const void* a1,
    const void* bih, const void* bhh,
    const void* g2, const void* be2, const void* m2, const void* v2, const void* a2,
    const void* bc,
    const void* g3, const void* be3, const void* m3, const void* v3, const void* a3,
    const void* bmu,
    void* out)
{
    __shared__ __align__(16) unsigned short hb[32 * LDP];
    __shared__ __align__(16) unsigned short yb[32 * LDP];
    __shared__ __align__(16) unsigned short zb[32 * LDP];
    if (g_flag) {
        fast_pipe<true >(hw, blin, g1, be1, m1, v1, a1, bih, bhh,
                         g2, be2, m2, v2, a2, bc, g3, be3, m3, v3, a3, bmu,
                         out, hb, yb, zb);
    } else {
        fast_pipe<false>(hw, blin, g1, be1, m1, v1, a1, bih, bhh,
                         g2, be2, m2, v2, a2, bc, g3, be3, m3, v3, a3, bmu,
                         out, hb, yb, zb);
    }
}

extern "C" void kernel_launch(void* const* d_in, const int* in_sizes, int n_in,
                              void* d_out, int out_size, void* d_ws, size_t ws_size,
                              hipStream_t stream) {
    (void)in_sizes; (void)n_in; (void)out_size; (void)d_ws; (void)ws_size;
    detect_dtype<<<dim3(1), dim3(1), 0, stream>>>(d_in[6]);
    prepack<<<dim3(308), dim3(256), 0, stream>>>(
        d_in[1], d_in[8], d_in[9], d_in[17], d_in[24]);
    comm_fast<<<dim3(256), dim3(1024), 0, stream>>>(
        d_in[0], d_in[2],
        d_in[3], d_in[4], d_in[5], d_in[6], d_in[7],
        d_in[10], d_in[11],
        d_in[12], d_in[13], d_in[14], d_in[15], d_in[16],
        d_in[18],
        d_in[19], d_in[20], d_in[21], d_in[22], d_in[23],
        d_in[25],
        d_out);
}